// Round 9
// baseline (57.540 us; speedup 1.0000x reference)
//
#include <hip/hip_runtime.h>

#define NN 4096
#define DD 256
#define MARGIN 0.5f

typedef __attribute__((ext_vector_type(8))) short bf16x8;  // 8 bf16 (4 VGPRs)
typedef __attribute__((ext_vector_type(4))) float f32x4;   // MFMA C/D

__device__ inline unsigned short f32_to_bf16_rne(float v) {
    unsigned int b = __float_as_uint(v);
    b += 0x7FFFu + ((b >> 16) & 1u);   // round-to-nearest-even
    return (unsigned short)(b >> 16);
}
__device__ inline float bf16_to_f32(unsigned short u) {
    return __uint_as_float(((unsigned int)u) << 16);
}

// ---------------------------------------------------------------------------
// Kernel A: per-row stats + bf16 convert + diagonal corrections.
// pb rows [0,4096)=p1, [4096,8192)=p2. nb[j]=||row_j||^2 (fp32).
// ai[i] = ||p1_i-p2_i||^2 - ||p1_i||^2 + MARGIN (fp32 exact).
// corr[i] = the two diagonal hinge terms (j==i, j==i+NN) recomputed from the
// SAME bf16-rounded values in fp32 (validated R7/R8: absmax 0.0).
// ---------------------------------------------------------------------------
__global__ __launch_bounds__(256) void stats_convert(
    const float* __restrict__ p1, const float* __restrict__ p2,
    unsigned short* __restrict__ pb, float* __restrict__ nb,
    float* __restrict__ ai, float* __restrict__ corr)
{
    const int wave = threadIdx.x >> 6;
    const int lane = threadIdx.x & 63;
    const int row  = blockIdx.x * 4 + wave;

    const float4 x = *(const float4*)&p1[(size_t)row * DD + lane * 4];
    const float4 y = *(const float4*)&p2[(size_t)row * DD + lane * 4];

    ushort4 xb, yb;
    xb.x = f32_to_bf16_rne(x.x); xb.y = f32_to_bf16_rne(x.y);
    xb.z = f32_to_bf16_rne(x.z); xb.w = f32_to_bf16_rne(x.w);
    yb.x = f32_to_bf16_rne(y.x); yb.y = f32_to_bf16_rne(y.y);
    yb.z = f32_to_bf16_rne(y.z); yb.w = f32_to_bf16_rne(y.w);
    *(ushort4*)&pb[(size_t)row * DD + lane * 4] = xb;
    *(ushort4*)&pb[(size_t)(NN + row) * DD + lane * 4] = yb;

    float s1 = x.x*x.x + x.y*x.y + x.z*x.z + x.w*x.w;
    float s2 = y.x*y.x + y.y*y.y + y.z*y.z + y.w*y.w;
    float dx = x.x-y.x, dy = x.y-y.y, dz = x.z-y.z, dw = x.w-y.w;
    float sa = dx*dx + dy*dy + dz*dz + dw*dw;

    // bf16-rounded self/cross dots (what the MFMA path sees on the diagonal)
    float xf0 = bf16_to_f32(xb.x), xf1 = bf16_to_f32(xb.y),
          xf2 = bf16_to_f32(xb.z), xf3 = bf16_to_f32(xb.w);
    float yf0 = bf16_to_f32(yb.x), yf1 = bf16_to_f32(yb.y),
          yf2 = bf16_to_f32(yb.z), yf3 = bf16_to_f32(yb.w);
    float s1b  = xf0*xf0 + xf1*xf1 + xf2*xf2 + xf3*xf3;
    float s12b = xf0*yf0 + xf1*yf1 + xf2*yf2 + xf3*yf3;

    #pragma unroll
    for (int off = 32; off > 0; off >>= 1) {
        s1  += __shfl_down(s1,  off);
        s2  += __shfl_down(s2,  off);
        sa  += __shfl_down(sa,  off);
        s1b += __shfl_down(s1b, off);
        s12b+= __shfl_down(s12b,off);
    }
    if (lane == 0) {
        nb[row]      = s1;
        nb[NN + row] = s2;
        ai[row]      = sa - s1 + MARGIN;
        const float t1 = fmaxf(sa - 2.f*s1 + MARGIN + 2.f*s1b, 0.f);
        const float t2 = fmaxf(sa - s1 - s2 + MARGIN + 2.f*s12b, 0.f);
        corr[row] = t1 + t2;
    }
}

// ---------------------------------------------------------------------------
// Kernel B: ZERO-LDS register GEMM + fused hinge. 512 blocks x 256 thr
// (4 waves 2Mx2N), 2 blocks/CU, NO __shared__ staging, NO barriers in the
// main loop: every wave is fully independent. A = 64 rows x full K in regs
// (a[4][8] = 128 VGPR). B-fragments load straight from L2 (b[8][2] = 64
// VGPR per 32-col strip); loads are issued kq-major so the compiler pipelines
// them with counted vmcnt against the 64 MFMAs (8 independent acc chains).
// L2 traffic 268 MB ~= MFMA floor; XCD mapping keeps the hot set at
// 2 jgroups x 512 rows (B, 512 KB) + A panels (2 MB) < 4 MB per-XCD L2.
// Epilogue: h = relu(2*dot + ai[i] - nb[j]) unconditional (diagonals via
// corr[], subtracted in final_reduce).
// ---------------------------------------------------------------------------
__global__ __launch_bounds__(256, 2) void gemm_hinge(
    const unsigned short* __restrict__ pb,
    const float* __restrict__ nb, const float* __restrict__ ai,
    float* __restrict__ partial)
{
    __shared__ float wsum[4];

    const int t    = threadIdx.x;
    const int lane = t & 63;
    const int wave = t >> 6;       // 0..3
    const int wm   = wave >> 1;    // 0..1 (M)
    const int wn   = wave & 1;     // 0..1 (N)

    // XCD mapping: bid = [b8][istripe:5][xcd:3]; jgroup = xcd*2 + b8.
    // Each XCD owns 2 jgroups x all 32 istripes -> hot B panel 512 KB.
    const int bid     = blockIdx.x;
    const int istripe = (bid >> 3) & 31;
    const int jgroup  = (bid & 7) * 2 + (bid >> 8);
    const int i0      = istripe * 128;

    const int lr = lane & 15;      // A row / B col within 16
    const int l4 = lane >> 4;      // 0..3
    const int lk = l4 * 8;         // k offset of lane's 8 contiguous bf16

    // ---- A fragments in registers: rows i0 + wm*64 + m*16 + lr, full K ----
    bf16x8 a[4][8];
    #pragma unroll
    for (int m = 0; m < 4; ++m) {
        const unsigned short* ar = pb + (size_t)(i0 + wm * 64 + m * 16 + lr) * DD + lk;
        #pragma unroll
        for (int kq = 0; kq < 8; ++kq)
            a[m][kq] = *(const bf16x8*)(ar + kq * 32);
    }

    // ---- ai preload (this lane's 16 fixed i-rows) ----
    const int r0 = l4 * 4;
    float aiv[4][4];
    #pragma unroll
    for (int m = 0; m < 4; ++m)
        #pragma unroll
        for (int r = 0; r < 4; ++r)
            aiv[m][r] = ai[i0 + wm * 64 + m * 16 + r0 + r];

    // ---- per-wave B base: col group = jgroup*512 + wn*32, this lane's row lr ----
    const unsigned short* bbase =
        pb + (size_t)(jgroup * 512 + wn * 32 + lr) * DD + lk;
    const float* nbb = nb + jgroup * 512 + wn * 32 + lr;

    float lsum = 0.f;

    #pragma unroll
    for (int jj = 0; jj < 8; ++jj) {
        // ---- B fragments for this 32-col strip, straight from global/L2 ----
        bf16x8 b[8][2];
        #pragma unroll
        for (int kq = 0; kq < 8; ++kq)
            #pragma unroll
            for (int n = 0; n < 2; ++n)
                b[kq][n] = *(const bf16x8*)
                    (bbase + (size_t)(jj * 64 + n * 16) * DD + kq * 32);

        f32x4 acc[4][2];
        #pragma unroll
        for (int m = 0; m < 4; ++m)
            #pragma unroll
            for (int n = 0; n < 2; ++n)
                acc[m][n] = (f32x4){0.f, 0.f, 0.f, 0.f};

        #pragma unroll
        for (int kq = 0; kq < 8; ++kq)
            #pragma unroll
            for (int m = 0; m < 4; ++m)
                #pragma unroll
                for (int n = 0; n < 2; ++n)
                    acc[m][n] = __builtin_amdgcn_mfma_f32_16x16x32_bf16(
                        a[m][kq], b[kq][n], acc[m][n], 0, 0, 0);

        // ---- hinge epilogue (unconditional; diagonals via corr[]) ----
        #pragma unroll
        for (int n = 0; n < 2; ++n) {
            const float nbj = nbb[jj * 64 + n * 16];
            #pragma unroll
            for (int m = 0; m < 4; ++m)
                #pragma unroll
                for (int r = 0; r < 4; ++r)
                    lsum += fmaxf(fmaf(2.f, acc[m][n][r], aiv[m][r] - nbj), 0.f);
        }
    }

    // ---- block reduction (deterministic) ----
    #pragma unroll
    for (int off = 32; off > 0; off >>= 1) lsum += __shfl_down(lsum, off);
    if (lane == 0) wsum[wave] = lsum;
    __syncthreads();
    if (t == 0)
        partial[bid] = wsum[0] + wsum[1] + wsum[2] + wsum[3];
}

// ---------------------------------------------------------------------------
// Kernel C: sum partials, subtract diagonal corrections, scale, write scalar.
// ---------------------------------------------------------------------------
__global__ __launch_bounds__(256) void final_reduce(
    const float* __restrict__ partial, const float* __restrict__ corr,
    float* __restrict__ out, float scale)
{
    const int t = threadIdx.x;
    float s = 0.f;
    for (int i = t; i < 512; i += 256) s += partial[i];
    for (int i = t; i < NN; i += 256) s -= corr[i];
    #pragma unroll
    for (int off = 32; off > 0; off >>= 1) s += __shfl_down(s, off);
    __shared__ float w[4];
    if ((t & 63) == 0) w[t >> 6] = s;
    __syncthreads();
    if (t == 0) out[0] = (w[0] + w[1] + w[2] + w[3]) * scale;
}

// ---------------------------------------------------------------------------
extern "C" void kernel_launch(void* const* d_in, const int* in_sizes, int n_in,
                              void* d_out, int out_size, void* d_ws, size_t ws_size,
                              hipStream_t stream) {
    const float* p1 = (const float*)d_in[0];
    const float* p2 = (const float*)d_in[1];
    float* out = (float*)d_out;

    char* ws = (char*)d_ws;
    unsigned short* pb = (unsigned short*)ws;                       // 4 MB (8192x256 bf16)
    float* nb      = (float*)(ws + (size_t)2 * NN * DD * 2);        // 32 KB
    float* ai      = nb + 2 * NN;                                   // 16 KB
    float* corr    = ai + NN;                                       // 16 KB
    float* partial = corr + NN;                                     // 2 KB
    const float scale = 1.0f / ((float)NN * (float)(NN - 1));

    stats_convert<<<NN / 4, 256, 0, stream>>>(p1, p2, pb, nb, ai, corr);
    gemm_hinge<<<512, 256, 0, stream>>>(pb, nb, ai, partial);
    final_reduce<<<1, 256, 0, stream>>>(partial, corr, out, scale);
}

// Round 10
// 39.040 us; speedup vs baseline: 1.4739x; 1.4739x over previous
//
#include <hip/hip_runtime.h>

#define NN 4096
#define DD 256
#define MARGIN 0.5f

typedef __attribute__((ext_vector_type(8))) short bf16x8;  // 8 bf16 (4 VGPRs)
typedef __attribute__((ext_vector_type(4))) float f32x4;   // MFMA C/D

__device__ inline unsigned short f32_to_bf16_rne(float v) {
    unsigned int b = __float_as_uint(v);
    b += 0x7FFFu + ((b >> 16) & 1u);   // round-to-nearest-even
    return (unsigned short)(b >> 16);
}
__device__ inline float bf16_to_f32(unsigned short u) {
    return __uint_as_float(((unsigned int)u) << 16);
}

// ---------------------------------------------------------------------------
// Kernel A: per-row stats + bf16 convert + diagonal corrections.
// pb rows [0,4096)=p1, [4096,8192)=p2. nb[j]=||row_j||^2 (fp32).
// ai[i] = ||p1_i-p2_i||^2 - ||p1_i||^2 + MARGIN (fp32 exact).
// corr[i] = the two diagonal hinge terms (j==i, j==i+NN) from the SAME
// bf16-rounded values in fp32 (validated R7-R9: absmax 0.0).
// ---------------------------------------------------------------------------
__global__ __launch_bounds__(256) void stats_convert(
    const float* __restrict__ p1, const float* __restrict__ p2,
    unsigned short* __restrict__ pb, float* __restrict__ nb,
    float* __restrict__ ai, float* __restrict__ corr)
{
    const int wave = threadIdx.x >> 6;
    const int lane = threadIdx.x & 63;
    const int row  = blockIdx.x * 4 + wave;

    const float4 x = *(const float4*)&p1[(size_t)row * DD + lane * 4];
    const float4 y = *(const float4*)&p2[(size_t)row * DD + lane * 4];

    ushort4 xb, yb;
    xb.x = f32_to_bf16_rne(x.x); xb.y = f32_to_bf16_rne(x.y);
    xb.z = f32_to_bf16_rne(x.z); xb.w = f32_to_bf16_rne(x.w);
    yb.x = f32_to_bf16_rne(y.x); yb.y = f32_to_bf16_rne(y.y);
    yb.z = f32_to_bf16_rne(y.z); yb.w = f32_to_bf16_rne(y.w);
    *(ushort4*)&pb[(size_t)row * DD + lane * 4] = xb;
    *(ushort4*)&pb[(size_t)(NN + row) * DD + lane * 4] = yb;

    float s1 = x.x*x.x + x.y*x.y + x.z*x.z + x.w*x.w;
    float s2 = y.x*y.x + y.y*y.y + y.z*y.z + y.w*y.w;
    float dx = x.x-y.x, dy = x.y-y.y, dz = x.z-y.z, dw = x.w-y.w;
    float sa = dx*dx + dy*dy + dz*dz + dw*dw;

    float xf0 = bf16_to_f32(xb.x), xf1 = bf16_to_f32(xb.y),
          xf2 = bf16_to_f32(xb.z), xf3 = bf16_to_f32(xb.w);
    float yf0 = bf16_to_f32(yb.x), yf1 = bf16_to_f32(yb.y),
          yf2 = bf16_to_f32(yb.z), yf3 = bf16_to_f32(yb.w);
    float s1b  = xf0*xf0 + xf1*xf1 + xf2*xf2 + xf3*xf3;
    float s12b = xf0*yf0 + xf1*yf1 + xf2*yf2 + xf3*yf3;

    #pragma unroll
    for (int off = 32; off > 0; off >>= 1) {
        s1  += __shfl_down(s1,  off);
        s2  += __shfl_down(s2,  off);
        sa  += __shfl_down(sa,  off);
        s1b += __shfl_down(s1b, off);
        s12b+= __shfl_down(s12b,off);
    }
    if (lane == 0) {
        nb[row]      = s1;
        nb[NN + row] = s2;
        ai[row]      = sa - s1 + MARGIN;
        const float t1 = fmaxf(sa - 2.f*s1 + MARGIN + 2.f*s1b, 0.f);
        const float t2 = fmaxf(sa - s1 - s2 + MARGIN + 2.f*s12b, 0.f);
        corr[row] = t1 + t2;
    }
}

// ---------------------------------------------------------------------------
// Kernel B: R5 core + counted-vmcnt pipeline (T3/T4) + setprio (T5).
// 512 blocks x 256 thr (4 waves 2Mx2N), 2 blocks/CU. A = 64 rows x full K
// in regs per wave (a[4][8]); B double-buffered LDS (2 x 32 KB) via
// global_load_lds w=16 with rule-21 both-sides XOR swizzle (R5-measured
// 0 conflicts). Pipeline: stage(jj+2) issued each iter; raw s_barrier pair
// with asm vmcnt(8) (NEVER 0 until last tile) keeps 8 loads in flight across
// barriers. VMEM ledger = stage loads only (nb preloaded to nbv[] regs).
// Epilogue unconditional; diagonals subtracted via corr[] in final_reduce.
// ---------------------------------------------------------------------------
__global__ __launch_bounds__(256, 2) void gemm_hinge(
    const unsigned short* __restrict__ pb,
    const float* __restrict__ nb, const float* __restrict__ ai,
    float* __restrict__ partial)
{
    __shared__ unsigned short Bs[2][64 * 256];   // 2 x 32 KB
    __shared__ float wsum[4];

    const int t    = threadIdx.x;
    const int lane = t & 63;
    const int wave = t >> 6;       // 0..3
    const int wm   = wave >> 1;    // 0..1 (M)
    const int wn   = wave & 1;     // 0..1 (N)

    // R5 XCD-bijective swizzle (512 = 8 XCD x 64): XCD x owns istripes
    // 4x..4x+3; all 16 jgroups of a stripe on one XCD.
    const int bid     = blockIdx.x;
    const int istripe = (bid & 7) * 4 + (bid >> 7);   // 0..31
    const int jgroup  = (bid >> 3) & 15;              // 0..15
    const int i0      = istripe * 128;
    const int jt0     = jgroup * 8;

    const int lr = lane & 15;      // A row / B col within 16
    const int l4 = lane >> 4;      // 0..3
    const int lk = l4 * 8;         // k offset of lane's 8 contiguous bf16

    // ---- B staging (rule-21 both-sides XOR swizzle, linear LDS dest) ----
    auto stage = [&](int sel, int jt) {
        const unsigned short* base = pb + (size_t)jt * 64 * DD;
        #pragma unroll
        for (int q = 0; q < 8; ++q) {
            const int c   = q * 256 + t;
            const int row = c >> 5;
            const int cw  = c & 31;
            const unsigned short* g = base + row * DD + ((cw ^ (row & 7)) * 8);
            __builtin_amdgcn_global_load_lds(
                (const __attribute__((address_space(1))) unsigned int*)g,
                (__attribute__((address_space(3))) unsigned int*)
                    &Bs[sel][(q * 256 + wave * 64) * 8],
                16, 0, 0);
        }
    };

    stage(0, jt0 + 0);             // earliest possible issue

    // ---- A fragments in registers: rows i0 + wm*64 + m*16 + lr, full K ----
    bf16x8 a[4][8];
    #pragma unroll
    for (int m = 0; m < 4; ++m) {
        const unsigned short* ar = pb + (size_t)(i0 + wm * 64 + m * 16 + lr) * DD + lk;
        #pragma unroll
        for (int kq = 0; kq < 8; ++kq)
            a[m][kq] = *(const bf16x8*)(ar + kq * 32);
    }

    // ---- ai / nb preload (removes vmem from the steady-state ledger) ----
    const int r0 = l4 * 4;
    float aiv[4][4];
    #pragma unroll
    for (int m = 0; m < 4; ++m)
        #pragma unroll
        for (int r = 0; r < 4; ++r)
            aiv[m][r] = ai[i0 + wm * 64 + m * 16 + r0 + r];

    float nbv[8][2];
    #pragma unroll
    for (int jj = 0; jj < 8; ++jj)
        #pragma unroll
        for (int n = 0; n < 2; ++n)
            nbv[jj][n] = nb[jgroup * 512 + jj * 64 + wn * 32 + n * 16 + lr];

    stage(1, jt0 + 1);

    // stage(0)+A+aiv+nbv complete; stage(1)'s 8 loads stay in flight.
    asm volatile("s_waitcnt vmcnt(8)" ::: "memory");
    __builtin_amdgcn_sched_barrier(0);
    __builtin_amdgcn_s_barrier();
    __builtin_amdgcn_sched_barrier(0);

    float lsum = 0.f;

    for (int jj = 0; jj < 8; ++jj) {
        const int sel = jj & 1;

        f32x4 acc[4][2];
        #pragma unroll
        for (int m = 0; m < 4; ++m)
            #pragma unroll
            for (int n = 0; n < 2; ++n)
                acc[m][n] = (f32x4){0.f, 0.f, 0.f, 0.f};

        __builtin_amdgcn_s_setprio(1);
        #pragma unroll
        for (int kq = 0; kq < 8; ++kq) {
            bf16x8 b[2];
            #pragma unroll
            for (int n = 0; n < 2; ++n) {
                const int row = wn * 32 + n * 16 + lr;
                const int cl  = kq * 4 + l4;
                b[n] = *(const bf16x8*)&Bs[sel][row * 256 + ((cl ^ (row & 7)) * 8)];
            }
            #pragma unroll
            for (int m = 0; m < 4; ++m)
                #pragma unroll
                for (int n = 0; n < 2; ++n)
                    acc[m][n] = __builtin_amdgcn_mfma_f32_16x16x32_bf16(
                        a[m][kq], b[n], acc[m][n], 0, 0, 0);
        }
        __builtin_amdgcn_s_setprio(0);

        // ---- hinge epilogue (registers only; unconditional) ----
        #pragma unroll
        for (int n = 0; n < 2; ++n) {
            const float nbj = nbv[jj][n];
            #pragma unroll
            for (int m = 0; m < 4; ++m)
                #pragma unroll
                for (int r = 0; r < 4; ++r)
                    lsum += fmaxf(fmaf(2.f, acc[m][n][r], aiv[m][r] - nbj), 0.f);
        }

        if (jj < 6) {
            // barrier 1: all waves done READING Bs[sel] -> safe to overwrite
            __builtin_amdgcn_s_barrier();
            __builtin_amdgcn_sched_barrier(0);
            stage(sel, jt0 + jj + 2);
            // wait: stage(jj+1) retired (8 oldest); stage(jj+2) stays in flight
            asm volatile("s_waitcnt vmcnt(8)" ::: "memory");
            __builtin_amdgcn_sched_barrier(0);
            // barrier 2: every wave has confirmed ITS stage(jj+1) loads
            __builtin_amdgcn_s_barrier();
            __builtin_amdgcn_sched_barrier(0);
        } else if (jj == 6) {
            // nothing left to stage; drain stage(7) and confirm across waves
            asm volatile("s_waitcnt vmcnt(0)" ::: "memory");
            __builtin_amdgcn_sched_barrier(0);
            __builtin_amdgcn_s_barrier();
            __builtin_amdgcn_sched_barrier(0);
        }
    }

    // ---- block reduction (deterministic) ----
    #pragma unroll
    for (int off = 32; off > 0; off >>= 1) lsum += __shfl_down(lsum, off);
    if (lane == 0) wsum[wave] = lsum;
    __syncthreads();
    if (t == 0)
        partial[bid] = wsum[0] + wsum[1] + wsum[2] + wsum[3];
}

// ---------------------------------------------------------------------------
// Kernel C: sum partials, subtract diagonal corrections, scale, write scalar.
// ---------------------------------------------------------------------------
__global__ __launch_bounds__(256) void final_reduce(
    const float* __restrict__ partial, const float* __restrict__ corr,
    float* __restrict__ out, float scale)
{
    const int t = threadIdx.x;
    float s = 0.f;
    for (int i = t; i < 512; i += 256) s += partial[i];
    for (int i = t; i < NN; i += 256) s -= corr[i];
    #pragma unroll
    for (int off = 32; off > 0; off >>= 1) s += __shfl_down(s, off);
    __shared__ float w[4];
    if ((t & 63) == 0) w[t >> 6] = s;
    __syncthreads();
    if (t == 0) out[0] = (w[0] + w[1] + w[2] + w[3]) * scale;
}

// ---------------------------------------------------------------------------
extern "C" void kernel_launch(void* const* d_in, const int* in_sizes, int n_in,
                              void* d_out, int out_size, void* d_ws, size_t ws_size,
                              hipStream_t stream) {
    const float* p1 = (const float*)d_in[0];
    const float* p2 = (const float*)d_in[1];
    float* out = (float*)d_out;

    char* ws = (char*)d_ws;
    unsigned short* pb = (unsigned short*)ws;                       // 4 MB (8192x256 bf16)
    float* nb      = (float*)(ws + (size_t)2 * NN * DD * 2);        // 32 KB
    float* ai      = nb + 2 * NN;                                   // 16 KB
    float* corr    = ai + NN;                                       // 16 KB
    float* partial = corr + NN;                                     // 2 KB
    const float scale = 1.0f / ((float)NN * (float)(NN - 1));

    stats_convert<<<NN / 4, 256, 0, stream>>>(p1, p2, pb, nb, ai, corr);
    gemm_hinge<<<512, 256, 0, stream>>>(pb, nb, ai, partial);
    final_reduce<<<1, 256, 0, stream>>>(partial, corr, out, scale);
}